// Round 5
// baseline (308.714 us; speedup 1.0000x reference)
//
#include <hip/hip_runtime.h>
#include <math.h>

#define D 128

typedef __attribute__((ext_vector_type(8))) short bf16x8;
typedef __attribute__((ext_vector_type(4))) float f32x4;
union U4 { uint4 u; bf16x8 f; };

__device__ __forceinline__ float blo(unsigned p){ return __uint_as_float(p << 16); }
__device__ __forceinline__ float bhi(unsigned p){ return __uint_as_float(p & 0xffff0000u); }
__device__ __forceinline__ unsigned bpack(float a, float b){
  unsigned x = __float_as_uint(a), y = __float_as_uint(b);
  x += 0x7fffu + ((x >> 16) & 1u);   // RNE
  y += 0x7fffu + ((y >> 16) & 1u);
  return (x >> 16) | (y & 0xffff0000u);
}

// d_out doubles as scratch: row i = 128 dwords.
//   dwords [i*128 ..  i*128+64)  : aggx row i (bf16 pairs)  -- written by k_agg
//   dwords [i*128+64 .. i*128+128): xb   row i (bf16 pairs)  -- written by k_prep
// k_gemm_norm reads both for its own rows (pre-barrier), writes final floats
// to the same rows (post-barrier). No cross-block hazard.

// ---- in-degree count ----
__global__ void k_deg(const int* __restrict__ ei, int* __restrict__ cnt, int E){
  int e = blockIdx.x*256 + threadIdx.x;
  if (e < E) atomicAdd(cnt + ei[E + e], 1);
}

// ---- exclusive prefix sum over cnt[N]: 3 kernels ----
__global__ void k_scan1(const int* __restrict__ cnt, int* __restrict__ off,
                        int* __restrict__ bsum, int N){
  __shared__ int sm[256];
  int i = blockIdx.x*256 + threadIdx.x;
  int v = (i < N) ? cnt[i] : 0;
  int acc = v;
  sm[threadIdx.x] = acc;
  __syncthreads();
  for (int s = 1; s < 256; s <<= 1){
    int t = (threadIdx.x >= s) ? sm[threadIdx.x - s] : 0;
    __syncthreads();
    acc += t;
    sm[threadIdx.x] = acc;
    __syncthreads();
  }
  if (i < N) off[i] = acc - v;
  if (threadIdx.x == 255) bsum[blockIdx.x] = acc;
}

__global__ void k_scan2(int* __restrict__ bsum, int nb){
  __shared__ int sm[512];
  int v = (threadIdx.x < nb) ? bsum[threadIdx.x] : 0;
  int acc = v;
  sm[threadIdx.x] = acc;
  __syncthreads();
  for (int s = 1; s < 512; s <<= 1){
    int t = (threadIdx.x >= s) ? sm[threadIdx.x - s] : 0;
    __syncthreads();
    acc += t;
    sm[threadIdx.x] = acc;
    __syncthreads();
  }
  if (threadIdx.x < nb) bsum[threadIdx.x] = acc - v;
}

__global__ void k_scan3(int* __restrict__ off, const int* __restrict__ bsum,
                        int* __restrict__ cursor, int N){
  int i = blockIdx.x*256 + threadIdx.x;
  if (i < N){
    int o = off[i] + bsum[blockIdx.x];
    off[i] = o;
    cursor[i] = o;
  }
}

// ---- xb[i] = bf16(x[i] * dis[i]); store in out upper half ----
__global__ void k_prep(const float* __restrict__ x, const int* __restrict__ cnt,
                       unsigned* __restrict__ out_u, int N){
  int idx = blockIdx.x*256 + threadIdx.x;   // N*32 total
  if (idx >= N*32) return;
  int row = idx >> 5, q = idx & 31;
  float dis = rsqrtf((float)(cnt[row] + 1));
  float4 xv = reinterpret_cast<const float4*>(x)[idx];
  uint2 r; r.x = bpack(xv.x*dis, xv.y*dis); r.y = bpack(xv.z*dis, xv.w*dis);
  reinterpret_cast<uint2*>(out_u)[(size_t)row*64 + 32 + q] = r;
}

// ---- W/RW -> bf16, transposed (Wt[c][k]) + XOR-swizzled, into ws ----
__global__ void k_wprep(const float* __restrict__ W, const float* __restrict__ RW,
                        unsigned* __restrict__ dst){
  int idx = blockIdx.x*256 + threadIdx.x;   // 16384 total
  int m = idx >> 13;
  int w = idx & 8191;
  int c = w >> 6, kd = w & 63;
  const float* src = m ? RW : W;
  float a = src[(2*kd)*128 + c];
  float b = src[(2*kd+1)*128 + c];
  dst[(m<<13) + c*64 + (kd ^ ((c & 7) << 2))] = bpack(a, b);
}

// ---- scatter edge src ids into CSR buckets (keyed by dst) ----
__global__ void k_fill(const int* __restrict__ ei, int* __restrict__ cursor,
                       int* __restrict__ elist, int E){
  int e = blockIdx.x*256 + threadIdx.x;
  if (e < E){
    int d = ei[E + e];
    int pos = atomicAdd(cursor + d, 1);
    elist[pos] = ei[e];
  }
}

// ---- one wave per node, 4 gathers in flight ----
__global__ __launch_bounds__(256) void k_agg(unsigned* __restrict__ out_u,
    const int* __restrict__ elist, const int* __restrict__ off,
    const int* __restrict__ cnt, int N){
  const int lane = threadIdx.x & 63;
  int wid = blockIdx.x*4 + (threadIdx.x >> 6);
  const int nw = gridDim.x*4;
  for (int i = wid; i < N; i += nw){
    int node = __builtin_amdgcn_readfirstlane(i);
    int o = off[node];
    int c = cnt[node];
    unsigned ps = out_u[(size_t)node*128 + 64 + lane];   // self-loop, issued early
    float a0 = 0.f, a1 = 0.f;
    for (int j0 = 0; j0 < c; j0 += 64){
      int m = c - j0; if (m > 64) m = 64;
      int li = lane < m ? lane : m-1;
      int sid = elist[o + j0 + li];
      for (int jj = 0; jj < m; jj += 4){
        int s0 = __shfl(sid, jj);
        int s1 = __shfl(sid, jj+1 < m ? jj+1 : m-1);
        int s2 = __shfl(sid, jj+2 < m ? jj+2 : m-1);
        int s3 = __shfl(sid, jj+3 < m ? jj+3 : m-1);
        unsigned p0 = out_u[(size_t)s0*128 + 64 + lane];
        unsigned p1 = out_u[(size_t)s1*128 + 64 + lane];
        unsigned p2 = out_u[(size_t)s2*128 + 64 + lane];
        unsigned p3 = out_u[(size_t)s3*128 + 64 + lane];
        if (jj+1 >= m) p1 = 0;        // wave-uniform masks
        if (jj+2 >= m) p2 = 0;
        if (jj+3 >= m) p3 = 0;
        a0 += blo(p0) + blo(p1) + blo(p2) + blo(p3);
        a1 += bhi(p0) + bhi(p1) + bhi(p2) + bhi(p3);
      }
    }
    a0 += blo(ps); a1 += bhi(ps);
    float dis = rsqrtf((float)(c + 1));
    out_u[(size_t)node*128 + lane] = bpack(a0*dis, a1*dis);
  }
}

// ---- one 128-row tile: MFMA gemm + epilogue; y packed to bf16 regs ----
__device__ __forceinline__ void gemm_tile(int rowbase, int N,
    const unsigned* __restrict__ out_u, const unsigned* lds,
    int lo, int hi,
    const float* __restrict__ bias, const float* __restrict__ rbias,
    const int* __restrict__ cnt,
    unsigned* __restrict__ yp, float* __restrict__ cs, float* __restrict__ cq)
{
  int arow = rowbase + lo; if (arow >= N) arow = N - 1;   // clamped rows excluded below
  U4 aggF[4], xbF[4];
  #pragma unroll
  for (int kk = 0; kk < 4; ++kk){
    aggF[kk].u = *(const uint4*)&out_u[(size_t)arow*128 + kk*16 + hi*4];
    xbF[kk].u  = *(const uint4*)&out_u[(size_t)arow*128 + 64 + kk*16 + hi*4];
  }
  f32x4 accA[8], accR[8];
  #pragma unroll
  for (int ct = 0; ct < 8; ++ct){
    accA[ct] = (f32x4){0.f,0.f,0.f,0.f};
    accR[ct] = (f32x4){0.f,0.f,0.f,0.f};
  }
  #pragma unroll
  for (int ct = 0; ct < 8; ++ct){
    const int c = ct*16 + lo;
    #pragma unroll
    for (int kk = 0; kk < 4; ++kk){
      int kd = (kk*16 + hi*4) ^ ((c & 7) << 2);
      U4 wf, rf;
      wf.u = *(const uint4*)&lds[c*64 + kd];
      rf.u = *(const uint4*)&lds[8192 + c*64 + kd];
      accA[ct] = __builtin_amdgcn_mfma_f32_16x16x32_bf16(aggF[kk].f, wf.f, accA[ct], 0,0,0);
      accR[ct] = __builtin_amdgcn_mfma_f32_16x16x32_bf16(xbF[kk].f, rf.f, accR[ct], 0,0,0);
    }
  }
  // epilogue: C/D layout col=lane&15, row=hi*4+reg
  float s_[4];
  #pragma unroll
  for (int j = 0; j < 4; ++j){
    int r = rowbase + hi*4 + j;
    int rc = r < N ? r : N - 1;
    s_[j] = sqrtf((float)(cnt[rc] + 1));   // undo dis scaling on residual
  }
  const int rb = rowbase + hi*4;
  #pragma unroll
  for (int ct = 0; ct < 8; ++ct){
    float bc  = bias[ct*16 + lo];
    float rbc = rbias[ct*16 + lo];
    float y0 = accA[ct][0] + bc + fmaxf(accR[ct][0]*s_[0] + rbc, 0.f);
    float y1 = accA[ct][1] + bc + fmaxf(accR[ct][1]*s_[1] + rbc, 0.f);
    float y2 = accA[ct][2] + bc + fmaxf(accR[ct][2]*s_[2] + rbc, 0.f);
    float y3 = accA[ct][3] + bc + fmaxf(accR[ct][3]*s_[3] + rbc, 0.f);
    if (rb + 0 < N){ cs[ct] += y0; cq[ct] += y0*y0; }
    if (rb + 1 < N){ cs[ct] += y1; cq[ct] += y1*y1; }
    if (rb + 2 < N){ cs[ct] += y2; cq[ct] += y2*y2; }
    if (rb + 3 < N){ cs[ct] += y3; cq[ct] += y3*y3; }
    yp[2*ct]   = bpack(y0, y1);
    yp[2*ct+1] = bpack(y2, y3);
  }
}

// ---- normalize one tile from register-resident packed y ----
__device__ __forceinline__ void norm_tile(int rowbase, int N, float* __restrict__ out,
    int lo, int hi, const float* sc, const unsigned* __restrict__ yp)
{
  const int rb = rowbase + hi*4;
  #pragma unroll
  for (int ct = 0; ct < 8; ++ct){
    int col = ct*16 + lo;
    float s = sc[col], t = sc[128 + col];
    float y0 = blo(yp[2*ct]),   y1 = bhi(yp[2*ct]);
    float y2 = blo(yp[2*ct+1]), y3 = bhi(yp[2*ct+1]);
    if (rb + 0 < N) out[(size_t)(rb+0)*128 + col] = y0*s + t;
    if (rb + 1 < N) out[(size_t)(rb+1)*128 + col] = y1*s + t;
    if (rb + 2 < N) out[(size_t)(rb+2)*128 + col] = y2*s + t;
    if (rb + 3 < N) out[(size_t)(rb+3)*128 + col] = y3*s + t;
  }
}

// ---- fused GEMM + BN stats + grid barrier + normalize ----
__global__ __launch_bounds__(512, 4) void k_gemm_norm(
    const unsigned* __restrict__ wsW,
    const float* __restrict__ bias, const float* __restrict__ rbias,
    const int* __restrict__ cnt,
    float* __restrict__ out, float* __restrict__ colsum,
    unsigned* __restrict__ bar,
    const float* __restrict__ gamma, const float* __restrict__ beta,
    int N, int nt, float fN)
{
  __shared__ unsigned lds[16384];   // 64KB weights; reused for reduce + sc later
  unsigned* out_u = reinterpret_cast<unsigned*>(out);
  for (int i = threadIdx.x; i < 16384; i += 512) lds[i] = wsW[i];
  __syncthreads();

  const int lane = threadIdx.x & 63;
  const int wave = threadIdx.x >> 6;
  const int lo = lane & 15, hi = lane >> 4;

  int t0 = blockIdx.x;
  int t1 = blockIdx.x + gridDim.x;
  bool has0 = (t0 < nt);
  bool has1 = (t1 < nt);
  int rb0 = t0*128 + wave*16;
  int rb1 = t1*128 + wave*16;

  unsigned yp0[16], yp1[16];
  float cs[8] = {0,0,0,0,0,0,0,0}, cq[8] = {0,0,0,0,0,0,0,0};

  if (has0) gemm_tile(rb0, N, out_u, lds, lo, hi, bias, rbias, cnt, yp0, cs, cq);
  if (has1) gemm_tile(rb1, N, out_u, lds, lo, hi, bias, rbias, cnt, yp1, cs, cq);

  // wave-reduce colsum partials (rows spread over lane bits 4-5)
  #pragma unroll
  for (int ct = 0; ct < 8; ++ct){
    cs[ct] += __shfl_xor(cs[ct], 16); cs[ct] += __shfl_xor(cs[ct], 32);
    cq[ct] += __shfl_xor(cq[ct], 16); cq[ct] += __shfl_xor(cq[ct], 32);
  }
  __syncthreads();                 // weights dead; reuse LDS as reduce buffer
  float* red = reinterpret_cast<float*>(lds);
  if (lane < 16){
    #pragma unroll
    for (int ct = 0; ct < 8; ++ct){
      int col = ct*16 + lane;
      red[wave*256 + 2*col]     = cs[ct];
      red[wave*256 + 2*col + 1] = cq[ct];
    }
  }
  __syncthreads();
  if (threadIdx.x < 256){
    float t = 0.f;
    #pragma unroll
    for (int w = 0; w < 8; ++w) t += red[w*256 + threadIdx.x];
    atomicAdd(colsum + threadIdx.x, t);
  }

  // ---- grid barrier (all 512 blocks co-resident by construction) ----
  __syncthreads();
  if (threadIdx.x == 0){
    __threadfence();
    __hip_atomic_fetch_add(bar, 1u, __ATOMIC_ACQ_REL, __HIP_MEMORY_SCOPE_AGENT);
    while (__hip_atomic_load(bar, __ATOMIC_ACQUIRE, __HIP_MEMORY_SCOPE_AGENT)
           < (unsigned)gridDim.x) {}
  }
  __syncthreads();

  // ---- BN finalize into LDS (atomic loads dodge stale-L2 across XCDs) ----
  float* sc = reinterpret_cast<float*>(lds);
  if (threadIdx.x < 128){
    int c = threadIdx.x;
    float s0 = __hip_atomic_load(&colsum[2*c],     __ATOMIC_RELAXED, __HIP_MEMORY_SCOPE_AGENT);
    float s1 = __hip_atomic_load(&colsum[2*c + 1], __ATOMIC_RELAXED, __HIP_MEMORY_SCOPE_AGENT);
    float mean = s0 / fN;
    float var  = fmaxf(s1 / fN - mean*mean, 0.f);
    float s = gamma[c] * rsqrtf(var + 1e-5f);
    sc[c] = s;
    sc[128 + c] = beta[c] - mean * s;
  }
  __syncthreads();

  if (has0) norm_tile(rb0, N, out, lo, hi, sc, yp0);
  if (has1) norm_tile(rb1, N, out, lo, hi, sc, yp1);
}

extern "C" void kernel_launch(void* const* d_in, const int* in_sizes, int n_in,
                              void* d_out, int out_size, void* d_ws, size_t ws_size,
                              hipStream_t stream){
  const float* x     = (const float*)d_in[0];
  const int*   ei    = (const int*)d_in[1];      // int64 staged as int32 by harness
  const float* W     = (const float*)d_in[2];
  const float* b     = (const float*)d_in[3];
  const float* RW    = (const float*)d_in[4];
  const float* rb    = (const float*)d_in[5];
  const float* gamma = (const float*)d_in[6];
  const float* beta  = (const float*)d_in[7];
  float* out = (float*)d_out;
  unsigned* out_u = (unsigned*)d_out;
  const int N = in_sizes[0] / D;
  const int E = in_sizes[1] / 2;

  char* ws = (char*)d_ws;
  size_t o = 0;
  auto alloc = [&](size_t bytes)->void*{
    void* p = ws + o;
    o += (bytes + 255) & ~size_t(255);
    return p;
  };
  int*      cnt    = (int*)alloc((size_t)N*4);
  int*      off    = (int*)alloc((size_t)N*4);
  int*      cursor = (int*)alloc((size_t)N*4);
  int*      bsum   = (int*)alloc(512*4);
  float*    colsum = (float*)alloc(256*4);       // interleaved [sum,sumsq] per col
  unsigned* bar    = (unsigned*)alloc(256);      // grid-barrier counter
  unsigned* wsW    = (unsigned*)alloc(16384*4);  // swizzled bf16 Wt|RWt
  int*      elist  = (int*)alloc((size_t)E*4);

  hipMemsetAsync(cnt, 0, (size_t)N*4, stream);
  hipMemsetAsync(colsum, 0, 256*4 + 256, stream);   // colsum + bar (contiguous)

  int egrid = (E + 255)/256;
  int nb = (N + 255)/256;
  int nt = (N + 127)/128;
  k_deg  <<<egrid, 256, 0, stream>>>(ei, cnt, E);
  k_scan1<<<nb,    256, 0, stream>>>(cnt, off, bsum, N);
  k_scan2<<<1,     512, 0, stream>>>(bsum, nb);
  k_scan3<<<nb,    256, 0, stream>>>(off, bsum, cursor, N);
  k_prep <<<(N*32 + 255)/256, 256, 0, stream>>>(x, cnt, out_u, N);
  k_wprep<<<64,    256, 0, stream>>>(W, RW, wsW);
  k_fill <<<egrid, 256, 0, stream>>>(ei, cursor, elist, E);
  k_agg  <<<4096,  256, 0, stream>>>(out_u, elist, off, cnt, N);
  k_gemm_norm<<<512, 512, 0, stream>>>(wsW, b, rb, cnt, out, colsum, bar,
                                       gamma, beta, N, nt, (float)N);
}

// Round 7
// 271.639 us; speedup vs baseline: 1.1365x; 1.1365x over previous
//
#include <hip/hip_runtime.h>
#include <math.h>

#define D 128

typedef __attribute__((ext_vector_type(8))) short bf16x8;
typedef __attribute__((ext_vector_type(4))) float f32x4;
union U4 { uint4 u; bf16x8 f; };

__device__ __forceinline__ float blo(unsigned p){ return __uint_as_float(p << 16); }
__device__ __forceinline__ float bhi(unsigned p){ return __uint_as_float(p & 0xffff0000u); }
__device__ __forceinline__ unsigned bpack(float a, float b){
  unsigned x = __float_as_uint(a), y = __float_as_uint(b);
  x += 0x7fffu + ((x >> 16) & 1u);   // RNE
  y += 0x7fffu + ((y >> 16) & 1u);
  return (x >> 16) | (y & 0xffff0000u);
}

// d_out doubles as scratch: row i = 128 dwords.
//   dwords [i*128 ..  i*128+64)  : aggx row i (bf16 pairs)  -- k_agg writes
//   dwords [i*128+64 .. i*128+128): xb   row i (bf16 pairs)  -- k_prep writes
// k_gemm reads both for its rows, then overwrites dwords [0..64) with packed
// bf16 y (coalesced). k_norm reads packed y, writes final f32 full row.

// ---- in-degree count ----
__global__ void k_deg(const int* __restrict__ ei, int* __restrict__ cnt, int E){
  int e = blockIdx.x*256 + threadIdx.x;
  if (e < E) atomicAdd(cnt + ei[E + e], 1);
}

// ---- exclusive prefix sum over cnt[N]: 3 kernels ----
__global__ void k_scan1(const int* __restrict__ cnt, int* __restrict__ off,
                        int* __restrict__ bsum, int N){
  __shared__ int sm[256];
  int i = blockIdx.x*256 + threadIdx.x;
  int v = (i < N) ? cnt[i] : 0;
  int acc = v;
  sm[threadIdx.x] = acc;
  __syncthreads();
  for (int s = 1; s < 256; s <<= 1){
    int t = (threadIdx.x >= s) ? sm[threadIdx.x - s] : 0;
    __syncthreads();
    acc += t;
    sm[threadIdx.x] = acc;
    __syncthreads();
  }
  if (i < N) off[i] = acc - v;
  if (threadIdx.x == 255) bsum[blockIdx.x] = acc;
}

__global__ void k_scan2(int* __restrict__ bsum, int nb){
  __shared__ int sm[512];
  int v = (threadIdx.x < nb) ? bsum[threadIdx.x] : 0;
  int acc = v;
  sm[threadIdx.x] = acc;
  __syncthreads();
  for (int s = 1; s < 512; s <<= 1){
    int t = (threadIdx.x >= s) ? sm[threadIdx.x - s] : 0;
    __syncthreads();
    acc += t;
    sm[threadIdx.x] = acc;
    __syncthreads();
  }
  if (threadIdx.x < nb) bsum[threadIdx.x] = acc - v;
}

__global__ void k_scan3(int* __restrict__ off, const int* __restrict__ bsum,
                        int* __restrict__ cursor, int N){
  int i = blockIdx.x*256 + threadIdx.x;
  if (i < N){
    int o = off[i] + bsum[blockIdx.x];
    off[i] = o;
    cursor[i] = o;
  }
}

// ---- xb[i] = bf16(x[i] * dis[i]); store in out upper half ----
__global__ void k_prep(const float* __restrict__ x, const int* __restrict__ cnt,
                       unsigned* __restrict__ out_u, int N){
  int idx = blockIdx.x*256 + threadIdx.x;   // N*32 total
  if (idx >= N*32) return;
  int row = idx >> 5, q = idx & 31;
  float dis = rsqrtf((float)(cnt[row] + 1));
  float4 xv = reinterpret_cast<const float4*>(x)[idx];
  uint2 r; r.x = bpack(xv.x*dis, xv.y*dis); r.y = bpack(xv.z*dis, xv.w*dis);
  reinterpret_cast<uint2*>(out_u)[(size_t)row*64 + 32 + q] = r;
}

// ---- W/RW -> bf16, transposed (Wt[c][k]) + XOR-swizzled, into ws ----
__global__ void k_wprep(const float* __restrict__ W, const float* __restrict__ RW,
                        unsigned* __restrict__ dst){
  int idx = blockIdx.x*256 + threadIdx.x;   // 16384 total
  int m = idx >> 13;
  int w = idx & 8191;
  int c = w >> 6, kd = w & 63;
  const float* src = m ? RW : W;
  float a = src[(2*kd)*128 + c];
  float b = src[(2*kd+1)*128 + c];
  dst[(m<<13) + c*64 + (kd ^ ((c & 7) << 2))] = bpack(a, b);
}

// ---- scatter edge src ids into CSR buckets (keyed by dst) ----
__global__ void k_fill(const int* __restrict__ ei, int* __restrict__ cursor,
                       int* __restrict__ elist, int E){
  int e = blockIdx.x*256 + threadIdx.x;
  if (e < E){
    int d = ei[E + e];
    int pos = atomicAdd(cursor + d, 1);
    elist[pos] = ei[e];
  }
}

// ---- one wave per node, 4 gathers in flight ----
__global__ __launch_bounds__(256) void k_agg(unsigned* __restrict__ out_u,
    const int* __restrict__ elist, const int* __restrict__ off,
    const int* __restrict__ cnt, int N){
  const int lane = threadIdx.x & 63;
  int wid = blockIdx.x*4 + (threadIdx.x >> 6);
  const int nw = gridDim.x*4;
  for (int i = wid; i < N; i += nw){
    int node = __builtin_amdgcn_readfirstlane(i);
    int o = off[node];
    int c = cnt[node];
    unsigned ps = out_u[(size_t)node*128 + 64 + lane];   // self-loop, issued early
    float a0 = 0.f, a1 = 0.f;
    for (int j0 = 0; j0 < c; j0 += 64){
      int m = c - j0; if (m > 64) m = 64;
      int li = lane < m ? lane : m-1;
      int sid = elist[o + j0 + li];
      for (int jj = 0; jj < m; jj += 4){
        int s0 = __shfl(sid, jj);
        int s1 = __shfl(sid, jj+1 < m ? jj+1 : m-1);
        int s2 = __shfl(sid, jj+2 < m ? jj+2 : m-1);
        int s3 = __shfl(sid, jj+3 < m ? jj+3 : m-1);
        unsigned p0 = out_u[(size_t)s0*128 + 64 + lane];
        unsigned p1 = out_u[(size_t)s1*128 + 64 + lane];
        unsigned p2 = out_u[(size_t)s2*128 + 64 + lane];
        unsigned p3 = out_u[(size_t)s3*128 + 64 + lane];
        if (jj+1 >= m) p1 = 0;        // wave-uniform masks
        if (jj+2 >= m) p2 = 0;
        if (jj+3 >= m) p3 = 0;
        a0 += blo(p0) + blo(p1) + blo(p2) + blo(p3);
        a1 += bhi(p0) + bhi(p1) + bhi(p2) + bhi(p3);
      }
    }
    a0 += blo(ps); a1 += bhi(ps);
    float dis = rsqrtf((float)(c + 1));
    out_u[(size_t)node*128 + lane] = bpack(a0*dis, a1*dis);
  }
}

// ---- MFMA GEMM: y = aggx@W + b + relu((xb@RW)*s + rb); bf16-packed coalesced
//      y-write via LDS transpose; BN partial sums to colsum ----
__global__ __launch_bounds__(512) void k_gemm(
    const unsigned* __restrict__ wsW,     // 16384 dwords: swizzled Wt | RWt
    const float* __restrict__ bias, const float* __restrict__ rbias,
    const int* __restrict__ cnt,
    float* __restrict__ out, float* __restrict__ colsum, int N)
{
  __shared__ unsigned lds[16384];   // 64KB: weights -> y-f32 tile -> reduce buf
  unsigned* out_u = reinterpret_cast<unsigned*>(out);
  for (int i = threadIdx.x; i < 16384; i += 512) lds[i] = wsW[i];
  __syncthreads();

  const int lane = threadIdx.x & 63;
  const int wave = threadIdx.x >> 6;
  const int lo = lane & 15, hi = lane >> 4;
  const int rowbase = blockIdx.x * 128 + wave * 16;

  int arow = rowbase + lo; if (arow >= N) arow = N - 1;   // clamped rows excluded
  U4 aggF[4], xbF[4];
  #pragma unroll
  for (int kk = 0; kk < 4; ++kk){
    aggF[kk].u = *(const uint4*)&out_u[(size_t)arow*128 + kk*16 + hi*4];
    xbF[kk].u  = *(const uint4*)&out_u[(size_t)arow*128 + 64 + kk*16 + hi*4];
  }

  f32x4 accA[8], accR[8];
  #pragma unroll
  for (int ct = 0; ct < 8; ++ct){
    accA[ct] = (f32x4){0.f,0.f,0.f,0.f};
    accR[ct] = (f32x4){0.f,0.f,0.f,0.f};
  }
  #pragma unroll
  for (int ct = 0; ct < 8; ++ct){
    const int c = ct*16 + lo;
    #pragma unroll
    for (int kk = 0; kk < 4; ++kk){
      int kd = (kk*16 + hi*4) ^ ((c & 7) << 2);
      U4 wf, rf;
      wf.u = *(const uint4*)&lds[c*64 + kd];
      rf.u = *(const uint4*)&lds[8192 + c*64 + kd];
      accA[ct] = __builtin_amdgcn_mfma_f32_16x16x32_bf16(aggF[kk].f, wf.f, accA[ct], 0,0,0);
      accR[ct] = __builtin_amdgcn_mfma_f32_16x16x32_bf16(xbF[kk].f, rf.f, accR[ct], 0,0,0);
    }
  }

  // epilogue: C/D layout col=lane&15, row=hi*4+reg. y stays in accA.
  float s_[4];
  #pragma unroll
  for (int j = 0; j < 4; ++j){
    int r = rowbase + hi*4 + j;
    int rc = r < N ? r : N - 1;
    s_[j] = sqrtf((float)(cnt[rc] + 1));   // undo dis scaling on residual
  }
  const int rb4 = rowbase + hi*4;
  float cs[8], cq[8];
  #pragma unroll
  for (int ct = 0; ct < 8; ++ct){
    cs[ct] = 0.f; cq[ct] = 0.f;
    float bc  = bias[ct*16 + lo];
    float rbc = rbias[ct*16 + lo];
    #pragma unroll
    for (int j = 0; j < 4; ++j){
      float y = accA[ct][j] + bc + fmaxf(accR[ct][j]*s_[j] + rbc, 0.f);
      if (rb4 + j < N){ cs[ct] += y; cq[ct] += y*y; }
      accA[ct][j] = y;
    }
  }

  // stage y (f32) into LDS: [local_row 0..127][col 0..127]
  __syncthreads();                  // all waves done with weight LDS
  float* yl = reinterpret_cast<float*>(lds);
  #pragma unroll
  for (int ct = 0; ct < 8; ++ct){
    #pragma unroll
    for (int j = 0; j < 4; ++j)
      yl[(wave*16 + hi*4 + j)*128 + ct*16 + lo] = accA[ct][j];
  }
  __syncthreads();

  // pack bf16 pairs, coalesced store: wave writes 256B runs
  const int rbB = blockIdx.x * 128;
  #pragma unroll
  for (int chunk = 0; chunk < 16; ++chunk){
    int g = chunk*512 + threadIdx.x;      // dword index in block's packed tile
    int lr = g >> 6, d = g & 63;
    int row = rbB + lr;
    if (row < N){
      float a = yl[lr*128 + 2*d], b = yl[lr*128 + 2*d + 1];
      out_u[(size_t)row*128 + d] = bpack(a, b);
    }
  }

  // BN partials: wave-reduce over lane bits 4-5, then LDS block reduce
  #pragma unroll
  for (int ct = 0; ct < 8; ++ct){
    cs[ct] += __shfl_xor(cs[ct], 16); cs[ct] += __shfl_xor(cs[ct], 32);
    cq[ct] += __shfl_xor(cq[ct], 16); cq[ct] += __shfl_xor(cq[ct], 32);
  }
  __syncthreads();                  // y tile consumed; reuse LDS
  float* red = reinterpret_cast<float*>(lds);
  if (lane < 16){
    #pragma unroll
    for (int ct = 0; ct < 8; ++ct){
      int col = ct*16 + lane;
      red[wave*256 + 2*col]     = cs[ct];
      red[wave*256 + 2*col + 1] = cq[ct];
    }
  }
  __syncthreads();
  if (threadIdx.x < 256){
    float t = 0.f;
    #pragma unroll
    for (int w = 0; w < 8; ++w) t += red[w*256 + threadIdx.x];
    atomicAdd(colsum + threadIdx.x, t);
  }
}

// ---- BN finalize (per-block) + read bf16 y in place, write f32 ----
__global__ __launch_bounds__(256) void k_norm(float* out, const float* __restrict__ colsum,
                       const float* __restrict__ gamma, const float* __restrict__ beta,
                       float fN, int N){
  __shared__ float sc[256];
  if (threadIdx.x < 128){
    int c = threadIdx.x;
    float mean = colsum[2*c] / fN;
    float var  = fmaxf(colsum[2*c + 1] / fN - mean*mean, 0.f);
    float s = gamma[c] * rsqrtf(var + 1e-5f);
    sc[c] = s;
    sc[128 + c] = beta[c] - mean * s;
  }
  __syncthreads();
  const int lane = threadIdx.x & 63;
  const int wv   = threadIdx.x >> 6;
  unsigned* out_u = reinterpret_cast<unsigned*>(out);  // same base ptr: order kept
  const int rowsPerIter = gridDim.x * 16;              // 4 waves * 4 rows
  for (int r0 = (blockIdx.x*4 + wv)*4; r0 < N; r0 += rowsPerIter){
    int rr = r0 + (lane >> 4);
    int d  = (lane & 15) * 4;          // packed dword offset
    if (rr < N){
      uint4 p = *reinterpret_cast<uint4*>(&out_u[(size_t)rr*128 + d]);
      int c0 = d*2;
      float4 o1, o2;
      o1.x = blo(p.x)*sc[c0+0] + sc[128+c0+0];
      o1.y = bhi(p.x)*sc[c0+1] + sc[128+c0+1];
      o1.z = blo(p.y)*sc[c0+2] + sc[128+c0+2];
      o1.w = bhi(p.y)*sc[c0+3] + sc[128+c0+3];
      o2.x = blo(p.z)*sc[c0+4] + sc[128+c0+4];
      o2.y = bhi(p.z)*sc[c0+5] + sc[128+c0+5];
      o2.z = blo(p.w)*sc[c0+6] + sc[128+c0+6];
      o2.w = bhi(p.w)*sc[c0+7] + sc[128+c0+7];
      *reinterpret_cast<float4*>(&out[(size_t)rr*128 + c0])     = o1;
      *reinterpret_cast<float4*>(&out[(size_t)rr*128 + c0 + 4]) = o2;
    }
  }
}

extern "C" void kernel_launch(void* const* d_in, const int* in_sizes, int n_in,
                              void* d_out, int out_size, void* d_ws, size_t ws_size,
                              hipStream_t stream){
  const float* x     = (const float*)d_in[0];
  const int*   ei    = (const int*)d_in[1];      // int64 staged as int32 by harness
  const float* W     = (const float*)d_in[2];
  const float* b     = (const float*)d_in[3];
  const float* RW    = (const float*)d_in[4];
  const float* rb    = (const float*)d_in[5];
  const float* gamma = (const float*)d_in[6];
  const float* beta  = (const float*)d_in[7];
  float* out = (float*)d_out;
  unsigned* out_u = (unsigned*)d_out;
  const int N = in_sizes[0] / D;
  const int E = in_sizes[1] / 2;

  char* ws = (char*)d_ws;
  size_t o = 0;
  auto alloc = [&](size_t bytes)->void*{
    void* p = ws + o;
    o += (bytes + 255) & ~size_t(255);
    return p;
  };
  int*      cnt    = (int*)alloc((size_t)N*4);
  int*      off    = (int*)alloc((size_t)N*4);
  int*      cursor = (int*)alloc((size_t)N*4);
  int*      bsum   = (int*)alloc(512*4);
  float*    colsum = (float*)alloc(256*4);       // interleaved [sum,sumsq] per col
  unsigned* wsW    = (unsigned*)alloc(16384*4);  // swizzled bf16 Wt|RWt
  int*      elist  = (int*)alloc((size_t)E*4);

  hipMemsetAsync(cnt, 0, (size_t)N*4, stream);
  hipMemsetAsync(colsum, 0, 256*4, stream);

  int egrid = (E + 255)/256;
  int nb = (N + 255)/256;
  k_deg  <<<egrid, 256, 0, stream>>>(ei, cnt, E);
  k_scan1<<<nb,    256, 0, stream>>>(cnt, off, bsum, N);
  k_scan2<<<1,     512, 0, stream>>>(bsum, nb);
  k_scan3<<<nb,    256, 0, stream>>>(off, bsum, cursor, N);
  k_prep <<<(N*32 + 255)/256, 256, 0, stream>>>(x, cnt, out_u, N);
  k_wprep<<<64,    256, 0, stream>>>(W, RW, wsW);
  k_fill <<<egrid, 256, 0, stream>>>(ei, cursor, elist, E);
  k_agg  <<<4096,  256, 0, stream>>>(out_u, elist, off, cnt, N);
  k_gemm <<<(N + 127)/128, 512, 0, stream>>>(wsW, b, rb, cnt, out, colsum, N);
  k_norm <<<2048,  256, 0, stream>>>(out, colsum, gamma, beta, (float)N, N);
}

// Round 8
// 264.586 us; speedup vs baseline: 1.1668x; 1.0267x over previous
//
#include <hip/hip_runtime.h>
#include <math.h>

#define D 128

typedef __attribute__((ext_vector_type(8))) short bf16x8;
typedef __attribute__((ext_vector_type(4))) float f32x4;
union U4 { uint4 u; bf16x8 f; };

__device__ __forceinline__ float blo(unsigned p){ return __uint_as_float(p << 16); }
__device__ __forceinline__ float bhi(unsigned p){ return __uint_as_float(p & 0xffff0000u); }
__device__ __forceinline__ unsigned bpack(float a, float b){
  unsigned x = __float_as_uint(a), y = __float_as_uint(b);
  x += 0x7fffu + ((x >> 16) & 1u);   // RNE
  y += 0x7fffu + ((y >> 16) & 1u);
  return (x >> 16) | (y & 0xffff0000u);
}

// d_out doubles as scratch: row i = 128 dwords.
//   dwords [i*128 ..  i*128+64)  : aggx row i (bf16 pairs)  -- k_agg writes
//   dwords [i*128+64 .. i*128+128): xb   row i (bf16 pairs)  -- k_prep3 writes
// k_gemm reads both for its rows, overwrites dwords [0..64) with packed bf16 y
// (coalesced). k_norm reads packed y, writes final f32 full row.

// ---- in-degree count ----
__global__ void k_deg(const int* __restrict__ ei, int* __restrict__ cnt, int E){
  int e = blockIdx.x*256 + threadIdx.x;
  if (e < E) atomicAdd(cnt + ei[E + e], 1);
}

// ---- scan step 1 (blocks < nb) + W/RW bf16-transpose-swizzle prep (blocks >= nb) ----
__global__ void k_scan1w(const int* __restrict__ cnt, int* __restrict__ off,
                         int* __restrict__ bsum, int N, int nb,
                         const float* __restrict__ W, const float* __restrict__ RW,
                         unsigned* __restrict__ wdst){
  if (blockIdx.x >= nb){
    int idx = (blockIdx.x - nb)*256 + threadIdx.x;   // 16384 total
    int m = idx >> 13;
    int w = idx & 8191;
    int c = w >> 6, kd = w & 63;
    const float* src = m ? RW : W;
    float a = src[(2*kd)*128 + c];
    float b = src[(2*kd+1)*128 + c];
    wdst[(m<<13) + c*64 + (kd ^ ((c & 7) << 2))] = bpack(a, b);
    return;
  }
  __shared__ int sm[256];
  int i = blockIdx.x*256 + threadIdx.x;
  int v = (i < N) ? cnt[i] : 0;
  int acc = v;
  sm[threadIdx.x] = acc;
  __syncthreads();
  for (int s = 1; s < 256; s <<= 1){
    int t = (threadIdx.x >= s) ? sm[threadIdx.x - s] : 0;
    __syncthreads();
    acc += t;
    sm[threadIdx.x] = acc;
    __syncthreads();
  }
  if (i < N) off[i] = acc - v;                 // block-local exclusive
  if (threadIdx.x == 255) bsum[blockIdx.x] = acc;
}

__global__ void k_scan2(int* __restrict__ bsum, int nb){
  __shared__ int sm[512];
  int v = (threadIdx.x < nb) ? bsum[threadIdx.x] : 0;
  int acc = v;
  sm[threadIdx.x] = acc;
  __syncthreads();
  for (int s = 1; s < 512; s <<= 1){
    int t = (threadIdx.x >= s) ? sm[threadIdx.x - s] : 0;
    __syncthreads();
    acc += t;
    sm[threadIdx.x] = acc;
    __syncthreads();
  }
  if (threadIdx.x < nb) bsum[threadIdx.x] = acc - v;   // exclusive block bases
}

// ---- scan step 3 (off/cursor finalize) + xb prep, merged ----
__global__ void k_prep3(const float* __restrict__ x, const int* __restrict__ cnt,
                        const int* __restrict__ bsum, int* __restrict__ off,
                        int* __restrict__ cursor, unsigned* __restrict__ out_u, int N){
  int idx = blockIdx.x*256 + threadIdx.x;   // N*32 total
  if (idx >= N*32) return;
  int row = idx >> 5, q = idx & 31;
  if (q == 0){
    int o = off[row] + bsum[row >> 8];
    off[row] = o;
    cursor[row] = o;
  }
  float dis = rsqrtf((float)(cnt[row] + 1));
  float4 xv = reinterpret_cast<const float4*>(x)[idx];
  uint2 r; r.x = bpack(xv.x*dis, xv.y*dis); r.y = bpack(xv.z*dis, xv.w*dis);
  reinterpret_cast<uint2*>(out_u)[(size_t)row*64 + 32 + q] = r;
}

// ---- XCD-sharded CSR fill: shard = blockIdx&7 owns dst range [N*s/8, N*(s+1)/8) ----
// All writes to a given elist/cursor region come from one XCD -> full-line
// writebacks instead of 16x-amplified partial-line scatter.
__global__ __launch_bounds__(256) void k_fill(const int* __restrict__ ei,
    int* __restrict__ cursor, int* __restrict__ elist, int E, int N){
  const int shard = blockIdx.x & 7;
  const int lo = (int)(((long long)N * shard) >> 3);
  const int hi = (int)(((long long)N * (shard + 1)) >> 3);
  const int nbs = gridDim.x >> 3;
  const int bi  = blockIdx.x >> 3;
  for (int e = bi*256 + threadIdx.x; e < E; e += nbs*256){
    int d = ei[E + e];
    if (d >= lo && d < hi){
      int pos = atomicAdd(cursor + d, 1);
      elist[pos] = ei[e];
    }
  }
}

// ---- one wave per node; uint2 gathers: half-wave per row, 8 neighbors in flight ----
__global__ __launch_bounds__(256) void k_agg(unsigned* __restrict__ out_u,
    const int* __restrict__ elist, const int* __restrict__ off,
    const int* __restrict__ cnt, int N){
  const int lane = threadIdx.x & 63;
  const int half = lane >> 5;        // 0: even neighbors, 1: odd neighbors
  const int hl   = lane & 31;        // dword-pair index within row
  int wid = blockIdx.x*4 + (threadIdx.x >> 6);
  const int nw = gridDim.x*4;
  for (int i = wid; i < N; i += nw){
    int node = __builtin_amdgcn_readfirstlane(i);
    int o = off[node];
    int c = cnt[node];
    uint2 ps = *(const uint2*)&out_u[(size_t)node*128 + 64 + 2*hl];  // self-loop
    float ax0=0.f, ax1=0.f, ay0=0.f, ay1=0.f;
    for (int j0 = 0; j0 < c; j0 += 64){
      int m = c - j0; if (m > 64) m = 64;
      int li = lane < m ? lane : m-1;
      int sid = elist[o + j0 + li];
      for (int jj = 0; jj < m; jj += 8){
        int n0 = jj + half, n1 = jj + 2 + half, n2 = jj + 4 + half, n3 = jj + 6 + half;
        int s0 = __shfl(sid, n0 < m ? n0 : m-1);
        int s1 = __shfl(sid, n1 < m ? n1 : m-1);
        int s2 = __shfl(sid, n2 < m ? n2 : m-1);
        int s3 = __shfl(sid, n3 < m ? n3 : m-1);
        uint2 p0 = *(const uint2*)&out_u[(size_t)s0*128 + 64 + 2*hl];
        uint2 p1 = *(const uint2*)&out_u[(size_t)s1*128 + 64 + 2*hl];
        uint2 p2 = *(const uint2*)&out_u[(size_t)s2*128 + 64 + 2*hl];
        uint2 p3 = *(const uint2*)&out_u[(size_t)s3*128 + 64 + 2*hl];
        if (n0 >= m){ p0.x = 0; p0.y = 0; }
        if (n1 >= m){ p1.x = 0; p1.y = 0; }
        if (n2 >= m){ p2.x = 0; p2.y = 0; }
        if (n3 >= m){ p3.x = 0; p3.y = 0; }
        ax0 += blo(p0.x)+blo(p1.x)+blo(p2.x)+blo(p3.x);
        ax1 += bhi(p0.x)+bhi(p1.x)+bhi(p2.x)+bhi(p3.x);
        ay0 += blo(p0.y)+blo(p1.y)+blo(p2.y)+blo(p3.y);
        ay1 += bhi(p0.y)+bhi(p1.y)+bhi(p2.y)+bhi(p3.y);
      }
    }
    if (half == 0){
      ax0 += blo(ps.x); ax1 += bhi(ps.x);
      ay0 += blo(ps.y); ay1 += bhi(ps.y);
    }
    ax0 += __shfl_xor(ax0, 32); ax1 += __shfl_xor(ax1, 32);
    ay0 += __shfl_xor(ay0, 32); ay1 += __shfl_xor(ay1, 32);
    float dis = rsqrtf((float)(c + 1));
    if (half == 0){
      uint2 r; r.x = bpack(ax0*dis, ax1*dis); r.y = bpack(ay0*dis, ay1*dis);
      *(uint2*)&out_u[(size_t)node*128 + 2*hl] = r;
    }
  }
}

// ---- MFMA GEMM: y = aggx@W + b + relu((xb@RW)*s + rb); bf16-packed coalesced
//      y-write via LDS transpose; BN partial sums to colsum ----
__global__ __launch_bounds__(512) void k_gemm(
    const unsigned* __restrict__ wsW,     // 16384 dwords: swizzled Wt | RWt
    const float* __restrict__ bias, const float* __restrict__ rbias,
    const int* __restrict__ cnt,
    float* __restrict__ out, float* __restrict__ colsum, int N)
{
  __shared__ unsigned lds[16384];   // 64KB: weights -> y-f32 tile -> reduce buf
  unsigned* out_u = reinterpret_cast<unsigned*>(out);
  for (int i = threadIdx.x; i < 16384; i += 512) lds[i] = wsW[i];
  __syncthreads();

  const int lane = threadIdx.x & 63;
  const int wave = threadIdx.x >> 6;
  const int lo = lane & 15, hi = lane >> 4;
  const int rowbase = blockIdx.x * 128 + wave * 16;

  int arow = rowbase + lo; if (arow >= N) arow = N - 1;   // clamped rows excluded
  U4 aggF[4], xbF[4];
  #pragma unroll
  for (int kk = 0; kk < 4; ++kk){
    aggF[kk].u = *(const uint4*)&out_u[(size_t)arow*128 + kk*16 + hi*4];
    xbF[kk].u  = *(const uint4*)&out_u[(size_t)arow*128 + 64 + kk*16 + hi*4];
  }

  f32x4 accA[8], accR[8];
  #pragma unroll
  for (int ct = 0; ct < 8; ++ct){
    accA[ct] = (f32x4){0.f,0.f,0.f,0.f};
    accR[ct] = (f32x4){0.f,0.f,0.f,0.f};
  }
  #pragma unroll
  for (int ct = 0; ct < 8; ++ct){
    const int c = ct*16 + lo;
    #pragma unroll
    for (int kk = 0; kk < 4; ++kk){
      int kd = (kk*16 + hi*4) ^ ((c & 7) << 2);
      U4 wf, rf;
      wf.u = *(const uint4*)&lds[c*64 + kd];
      rf.u = *(const uint4*)&lds[8192 + c*64 + kd];
      accA[ct] = __builtin_amdgcn_mfma_f32_16x16x32_bf16(aggF[kk].f, wf.f, accA[ct], 0,0,0);
      accR[ct] = __builtin_amdgcn_mfma_f32_16x16x32_bf16(xbF[kk].f, rf.f, accR[ct], 0,0,0);
    }
  }

  // epilogue: C/D layout col=lane&15, row=hi*4+reg. y stays in accA.
  float s_[4];
  #pragma unroll
  for (int j = 0; j < 4; ++j){
    int r = rowbase + hi*4 + j;
    int rc = r < N ? r : N - 1;
    s_[j] = sqrtf((float)(cnt[rc] + 1));   // undo dis scaling on residual
  }
  const int rb4 = rowbase + hi*4;
  float cs[8], cq[8];
  #pragma unroll
  for (int ct = 0; ct < 8; ++ct){
    cs[ct] = 0.f; cq[ct] = 0.f;
    float bc  = bias[ct*16 + lo];
    float rbc = rbias[ct*16 + lo];
    #pragma unroll
    for (int j = 0; j < 4; ++j){
      float y = accA[ct][j] + bc + fmaxf(accR[ct][j]*s_[j] + rbc, 0.f);
      if (rb4 + j < N){ cs[ct] += y; cq[ct] += y*y; }
      accA[ct][j] = y;
    }
  }

  // stage y (f32) into LDS: [local_row 0..127][col 0..127]
  __syncthreads();                  // all waves done with weight LDS
  float* yl = reinterpret_cast<float*>(lds);
  #pragma unroll
  for (int ct = 0; ct < 8; ++ct){
    #pragma unroll
    for (int j = 0; j < 4; ++j)
      yl[(wave*16 + hi*4 + j)*128 + ct*16 + lo] = accA[ct][j];
  }
  __syncthreads();

  // pack bf16 pairs, coalesced store: wave writes 256B runs
  const int rbB = blockIdx.x * 128;
  #pragma unroll
  for (int chunk = 0; chunk < 16; ++chunk){
    int g = chunk*512 + threadIdx.x;      // dword index in block's packed tile
    int lr = g >> 6, d = g & 63;
    int row = rbB + lr;
    if (row < N){
      float a = yl[lr*128 + 2*d], b = yl[lr*128 + 2*d + 1];
      out_u[(size_t)row*128 + d] = bpack(a, b);
    }
  }

  // BN partials: wave-reduce over lane bits 4-5, then LDS block reduce
  #pragma unroll
  for (int ct = 0; ct < 8; ++ct){
    cs[ct] += __shfl_xor(cs[ct], 16); cs[ct] += __shfl_xor(cs[ct], 32);
    cq[ct] += __shfl_xor(cq[ct], 16); cq[ct] += __shfl_xor(cq[ct], 32);
  }
  __syncthreads();                  // y tile consumed; reuse LDS
  float* red = reinterpret_cast<float*>(lds);
  if (lane < 16){
    #pragma unroll
    for (int ct = 0; ct < 8; ++ct){
      int col = ct*16 + lane;
      red[wave*256 + 2*col]     = cs[ct];
      red[wave*256 + 2*col + 1] = cq[ct];
    }
  }
  __syncthreads();
  if (threadIdx.x < 256){
    float t = 0.f;
    #pragma unroll
    for (int w = 0; w < 8; ++w) t += red[w*256 + threadIdx.x];
    atomicAdd(colsum + threadIdx.x, t);
  }
}

// ---- BN finalize (per-block) + read bf16 y in place, write f32 ----
__global__ __launch_bounds__(256) void k_norm(float* out, const float* __restrict__ colsum,
                       const float* __restrict__ gamma, const float* __restrict__ beta,
                       float fN, int N){
  __shared__ float sc[256];
  if (threadIdx.x < 128){
    int c = threadIdx.x;
    float mean = colsum[2*c] / fN;
    float var  = fmaxf(colsum[2*c + 1] / fN - mean*mean, 0.f);
    float s = gamma[c] * rsqrtf(var + 1e-5f);
    sc[c] = s;
    sc[128 + c] = beta[c] - mean * s;
  }
  __syncthreads();
  const int lane = threadIdx.x & 63;
  const int wv   = threadIdx.x >> 6;
  unsigned* out_u = reinterpret_cast<unsigned*>(out);
  const int rowsPerIter = gridDim.x * 16;              // 4 waves * 4 rows
  for (int r0 = (blockIdx.x*4 + wv)*4; r0 < N; r0 += rowsPerIter){
    int rr = r0 + (lane >> 4);
    int d  = (lane & 15) * 4;          // packed dword offset
    if (rr < N){
      uint4 p = *reinterpret_cast<uint4*>(&out_u[(size_t)rr*128 + d]);
      int c0 = d*2;
      float4 o1, o2;
      o1.x = blo(p.x)*sc[c0+0] + sc[128+c0+0];
      o1.y = bhi(p.x)*sc[c0+1] + sc[128+c0+1];
      o1.z = blo(p.y)*sc[c0+2] + sc[128+c0+2];
      o1.w = bhi(p.y)*sc[c0+3] + sc[128+c0+3];
      o2.x = blo(p.z)*sc[c0+4] + sc[128+c0+4];
      o2.y = bhi(p.z)*sc[c0+5] + sc[128+c0+5];
      o2.z = blo(p.w)*sc[c0+6] + sc[128+c0+6];
      o2.w = bhi(p.w)*sc[c0+7] + sc[128+c0+7];
      *reinterpret_cast<float4*>(&out[(size_t)rr*128 + c0])     = o1;
      *reinterpret_cast<float4*>(&out[(size_t)rr*128 + c0 + 4]) = o2;
    }
  }
}

extern "C" void kernel_launch(void* const* d_in, const int* in_sizes, int n_in,
                              void* d_out, int out_size, void* d_ws, size_t ws_size,
                              hipStream_t stream){
  const float* x     = (const float*)d_in[0];
  const int*   ei    = (const int*)d_in[1];      // int64 staged as int32 by harness
  const float* W     = (const float*)d_in[2];
  const float* b     = (const float*)d_in[3];
  const float* RW    = (const float*)d_in[4];
  const float* rb    = (const float*)d_in[5];
  const float* gamma = (const float*)d_in[6];
  const float* beta  = (const float*)d_in[7];
  float* out = (float*)d_out;
  unsigned* out_u = (unsigned*)d_out;
  const int N = in_sizes[0] / D;
  const int E = in_sizes[1] / 2;

  char* ws = (char*)d_ws;
  size_t o = 0;
  auto alloc = [&](size_t bytes)->void*{
    void* p = ws + o;
    o += (bytes + 255) & ~size_t(255);
    return p;
  };
  float*    colsum = (float*)alloc(256*4);       // interleaved [sum,sumsq]; FIRST
  int*      cnt    = (int*)alloc((size_t)N*4);   // adjacent to colsum: one memset
  int*      off    = (int*)alloc((size_t)N*4);
  int*      cursor = (int*)alloc((size_t)N*4);
  int*      bsum   = (int*)alloc(512*4);
  unsigned* wsW    = (unsigned*)alloc(16384*4);  // swizzled bf16 Wt|RWt
  int*      elist  = (int*)alloc((size_t)E*4);

  hipMemsetAsync(ws, 0, 1024 + (size_t)N*4, stream);   // colsum + cnt in one shot

  int egrid = (E + 255)/256;
  int nb = (N + 255)/256;
  k_deg   <<<egrid,   256, 0, stream>>>(ei, cnt, E);
  k_scan1w<<<nb + 64, 256, 0, stream>>>(cnt, off, bsum, N, nb, W, RW, wsW);
  k_scan2 <<<1,       512, 0, stream>>>(bsum, nb);
  k_prep3 <<<(N*32 + 255)/256, 256, 0, stream>>>(x, cnt, bsum, off, cursor, out_u, N);
  k_fill  <<<512,     256, 0, stream>>>(ei, cursor, elist, E, N);
  k_agg   <<<4096,    256, 0, stream>>>(out_u, elist, off, cnt, N);
  k_gemm  <<<(N + 127)/128, 512, 0, stream>>>(wsW, b, rb, cnt, out, colsum, N);
  k_norm  <<<2048,    256, 0, stream>>>(out, colsum, gamma, beta, (float)N, N);
}

// Round 10
// 258.042 us; speedup vs baseline: 1.1964x; 1.0254x over previous
//
#include <hip/hip_runtime.h>
#include <math.h>

#define D 128

typedef __attribute__((ext_vector_type(8))) short bf16x8;
typedef __attribute__((ext_vector_type(4))) float f32x4;
union U4 { uint4 u; bf16x8 f; };

__device__ __forceinline__ float blo(unsigned p){ return __uint_as_float(p << 16); }
__device__ __forceinline__ float bhi(unsigned p){ return __uint_as_float(p & 0xffff0000u); }
__device__ __forceinline__ unsigned bpack(float a, float b){
  unsigned x = __float_as_uint(a), y = __float_as_uint(b);
  x += 0x7fffu + ((x >> 16) & 1u);   // RNE
  y += 0x7fffu + ((y >> 16) & 1u);
  return (x >> 16) | (y & 0xffff0000u);
}

// d_out doubles as scratch: row i = 128 dwords.
//   dwords [i*128 ..  i*128+64)  : aggx row i (bf16 pairs)  -- k_agg writes
//   dwords [i*128+64 .. i*128+128): xb   row i (bf16 pairs)  -- k_alloc writes
// k_gemm reads both for its rows, overwrites dwords [0..64) with packed bf16 y
// (coalesced). k_norm reads packed y, writes final f32 full row.
//
// elist layout: node-group g = node>>13 owns region [g*gcap, g*gcap + cnt_g).
// Bases inside a group allocated order-free by atomic bump (no prefix scan).

// ---- in-degree count ----
__global__ void k_deg(const int* __restrict__ ei, int* __restrict__ cnt, int E){
  int e = blockIdx.x*256 + threadIdx.x;
  if (e < E) atomicAdd(cnt + ei[E + e], 1);
}

// ---- fused, order-free: [0,nb) off/cursor alloc; [nb,nb+64) W/RW prep; rest xb ----
__global__ __launch_bounds__(256) void k_alloc(
    const int* __restrict__ cnt, int* __restrict__ off, int* __restrict__ cursor,
    int* __restrict__ gcur, int gcap,
    const float* __restrict__ W, const float* __restrict__ RW, unsigned* __restrict__ wdst,
    const float* __restrict__ x, unsigned* __restrict__ out_u, int N, int nb)
{
  int b = blockIdx.x;
  if (b < nb){
    // block-local inclusive scan of cnt; one atomic bump per block for the base.
    // 256 | 8192 so a block never straddles a node-group boundary.
    __shared__ int sm[256];
    __shared__ int sbase;
    int i = b*256 + threadIdx.x;
    int v = (i < N) ? cnt[i] : 0;
    int acc = v;
    sm[threadIdx.x] = acc;
    __syncthreads();
    for (int s = 1; s < 256; s <<= 1){
      int t = (threadIdx.x >= s) ? sm[threadIdx.x - s] : 0;
      __syncthreads();
      acc += t;
      sm[threadIdx.x] = acc;
      __syncthreads();
    }
    if (threadIdx.x == 255){
      int g = (b*256) >> 13;
      sbase = g*gcap + atomicAdd(&gcur[g], acc);   // acc == block total here
    }
    __syncthreads();
    int o = sbase + acc - v;   // exclusive within block + block base
    if (i < N){ off[i] = o; cursor[i] = o; }
    return;
  }
  b -= nb;
  if (b < 64){
    // W/RW -> bf16, transposed (Wt[c][k]) + XOR-swizzled
    int idx = b*256 + threadIdx.x;   // 16384 total
    int m = idx >> 13;
    int w = idx & 8191;
    int c = w >> 6, kd = w & 63;
    const float* src = m ? RW : W;
    float a  = src[(2*kd)*128 + c];
    float bb = src[(2*kd+1)*128 + c];
    wdst[(m<<13) + c*64 + (kd ^ ((c & 7) << 2))] = bpack(a, bb);
    return;
  }
  b -= 64;
  // xb[i] = bf16(x[i] * dis[i]); store in out upper half
  int idx = b*256 + threadIdx.x;   // N*32 total
  if (idx >= N*32) return;
  int row = idx >> 5, q = idx & 31;
  float dis = rsqrtf((float)(cnt[row] + 1));
  float4 xv = reinterpret_cast<const float4*>(x)[idx];
  uint2 r; r.x = bpack(xv.x*dis, xv.y*dis); r.y = bpack(xv.z*dis, xv.w*dis);
  reinterpret_cast<uint2*>(out_u)[(size_t)row*64 + 32 + q] = r;
}

// ---- XCD-sharded CSR fill: team blockIdx&7 owns node-groups with (g&7)==team ----
// Each elist group-region is written by exactly one team (one XCD) -> full-line
// writebacks instead of 16x-amplified partial-line scatter.
__global__ __launch_bounds__(256) void k_fill(const int* __restrict__ ei,
    int* __restrict__ cursor, int* __restrict__ elist, int E){
  const int team = blockIdx.x & 7;
  const int nbs = gridDim.x >> 3;
  const int bi  = blockIdx.x >> 3;
  for (int e = bi*256 + threadIdx.x; e < E; e += nbs*256){
    int d = ei[E + e];
    if (((d >> 13) & 7) == team){
      int pos = atomicAdd(cursor + d, 1);
      elist[pos] = ei[e];
    }
  }
}

// ---- one wave per node; uint2 gathers: half-wave per row, 8 neighbors in flight ----
__global__ __launch_bounds__(256) void k_agg(unsigned* __restrict__ out_u,
    const int* __restrict__ elist, const int* __restrict__ off,
    const int* __restrict__ cnt, int N){
  const int lane = threadIdx.x & 63;
  const int half = lane >> 5;        // 0: even neighbors, 1: odd neighbors
  const int hl   = lane & 31;        // dword-pair index within row
  int wid = blockIdx.x*4 + (threadIdx.x >> 6);
  const int nw = gridDim.x*4;
  for (int i = wid; i < N; i += nw){
    int node = __builtin_amdgcn_readfirstlane(i);
    int o = off[node];
    int c = cnt[node];
    uint2 ps = *(const uint2*)&out_u[(size_t)node*128 + 64 + 2*hl];  // self-loop
    float ax0=0.f, ax1=0.f, ay0=0.f, ay1=0.f;
    for (int j0 = 0; j0 < c; j0 += 64){
      int m = c - j0; if (m > 64) m = 64;
      int li = lane < m ? lane : m-1;
      int sid = elist[o + j0 + li];
      for (int jj = 0; jj < m; jj += 8){
        int n0 = jj + half, n1 = jj + 2 + half, n2 = jj + 4 + half, n3 = jj + 6 + half;
        int s0 = __shfl(sid, n0 < m ? n0 : m-1);
        int s1 = __shfl(sid, n1 < m ? n1 : m-1);
        int s2 = __shfl(sid, n2 < m ? n2 : m-1);
        int s3 = __shfl(sid, n3 < m ? n3 : m-1);
        uint2 p0 = *(const uint2*)&out_u[(size_t)s0*128 + 64 + 2*hl];
        uint2 p1 = *(const uint2*)&out_u[(size_t)s1*128 + 64 + 2*hl];
        uint2 p2 = *(const uint2*)&out_u[(size_t)s2*128 + 64 + 2*hl];
        uint2 p3 = *(const uint2*)&out_u[(size_t)s3*128 + 64 + 2*hl];
        if (n0 >= m){ p0.x = 0; p0.y = 0; }
        if (n1 >= m){ p1.x = 0; p1.y = 0; }
        if (n2 >= m){ p2.x = 0; p2.y = 0; }
        if (n3 >= m){ p3.x = 0; p3.y = 0; }
        ax0 += blo(p0.x)+blo(p1.x)+blo(p2.x)+blo(p3.x);
        ax1 += bhi(p0.x)+bhi(p1.x)+bhi(p2.x)+bhi(p3.x);
        ay0 += blo(p0.y)+blo(p1.y)+blo(p2.y)+blo(p3.y);
        ay1 += bhi(p0.y)+bhi(p1.y)+bhi(p2.y)+bhi(p3.y);
      }
    }
    if (half == 0){
      ax0 += blo(ps.x); ax1 += bhi(ps.x);
      ay0 += blo(ps.y); ay1 += bhi(ps.y);
    }
    ax0 += __shfl_xor(ax0, 32); ax1 += __shfl_xor(ax1, 32);
    ay0 += __shfl_xor(ay0, 32); ay1 += __shfl_xor(ay1, 32);
    float dis = rsqrtf((float)(c + 1));
    if (half == 0){
      uint2 r; r.x = bpack(ax0*dis, ax1*dis); r.y = bpack(ay0*dis, ay1*dis);
      *(uint2*)&out_u[(size_t)node*128 + 2*hl] = r;
    }
  }
}

// ---- MFMA GEMM: y = aggx@W + b + relu((xb@RW)*s + rb); bf16-packed coalesced
//      y-write via LDS transpose; BN partial sums to colsum ----
__global__ __launch_bounds__(512) void k_gemm(
    const unsigned* __restrict__ wsW,     // 16384 dwords: swizzled Wt | RWt
    const float* __restrict__ bias, const float* __restrict__ rbias,
    const int* __restrict__ cnt,
    float* __restrict__ out, float* __restrict__ colsum, int N)
{
  __shared__ unsigned lds[16384];   // 64KB: weights -> y-f32 tile -> reduce buf
  unsigned* out_u = reinterpret_cast<unsigned*>(out);
  for (int i = threadIdx.x; i < 16384; i += 512) lds[i] = wsW[i];
  __syncthreads();

  const int lane = threadIdx.x & 63;
  const int wave = threadIdx.x >> 6;
  const int lo = lane & 15, hi = lane >> 4;
  const int rowbase = blockIdx.x * 128 + wave * 16;

  int arow = rowbase + lo; if (arow >= N) arow = N - 1;   // clamped rows excluded
  U4 aggF[4], xbF[4];
  #pragma unroll
  for (int kk = 0; kk < 4; ++kk){
    aggF[kk].u = *(const uint4*)&out_u[(size_t)arow*128 + kk*16 + hi*4];
    xbF[kk].u  = *(const uint4*)&out_u[(size_t)arow*128 + 64 + kk*16 + hi*4];
  }

  f32x4 accA[8], accR[8];
  #pragma unroll
  for (int ct = 0; ct < 8; ++ct){
    accA[ct] = (f32x4){0.f,0.f,0.f,0.f};
    accR[ct] = (f32x4){0.f,0.f,0.f,0.f};
  }
  #pragma unroll
  for (int ct = 0; ct < 8; ++ct){
    const int c = ct*16 + lo;
    #pragma unroll
    for (int kk = 0; kk < 4; ++kk){
      int kd = (kk*16 + hi*4) ^ ((c & 7) << 2);
      U4 wf, rf;
      wf.u = *(const uint4*)&lds[c*64 + kd];
      rf.u = *(const uint4*)&lds[8192 + c*64 + kd];
      accA[ct] = __builtin_amdgcn_mfma_f32_16x16x32_bf16(aggF[kk].f, wf.f, accA[ct], 0,0,0);
      accR[ct] = __builtin_amdgcn_mfma_f32_16x16x32_bf16(xbF[kk].f, rf.f, accR[ct], 0,0,0);
    }
  }

  // epilogue: C/D layout col=lane&15, row=hi*4+reg. y stays in accA.
  float s_[4];
  #pragma unroll
  for (int j = 0; j < 4; ++j){
    int r = rowbase + hi*4 + j;
    int rc = r < N ? r : N - 1;
    s_[j] = sqrtf((float)(cnt[rc] + 1));   // undo dis scaling on residual
  }
  const int rb4 = rowbase + hi*4;
  float cs[8], cq[8];
  #pragma unroll
  for (int ct = 0; ct < 8; ++ct){
    cs[ct] = 0.f; cq[ct] = 0.f;
    float bc  = bias[ct*16 + lo];
    float rbc = rbias[ct*16 + lo];
    #pragma unroll
    for (int j = 0; j < 4; ++j){
      float y = accA[ct][j] + bc + fmaxf(accR[ct][j]*s_[j] + rbc, 0.f);
      if (rb4 + j < N){ cs[ct] += y; cq[ct] += y*y; }
      accA[ct][j] = y;
    }
  }

  // stage y (f32) into LDS: [local_row 0..127][col 0..127]
  __syncthreads();                  // all waves done with weight LDS
  float* yl = reinterpret_cast<float*>(lds);
  #pragma unroll
  for (int ct = 0; ct < 8; ++ct){
    #pragma unroll
    for (int j = 0; j < 4; ++j)
      yl[(wave*16 + hi*4 + j)*128 + ct*16 + lo] = accA[ct][j];
  }
  __syncthreads();

  // pack bf16 pairs, coalesced store: wave writes 256B runs
  const int rbB = blockIdx.x * 128;
  #pragma unroll
  for (int chunk = 0; chunk < 16; ++chunk){
    int g = chunk*512 + threadIdx.x;      // dword index in block's packed tile
    int lr = g >> 6, d = g & 63;
    int row = rbB + lr;
    if (row < N){
      float a = yl[lr*128 + 2*d], b = yl[lr*128 + 2*d + 1];
      out_u[(size_t)row*128 + d] = bpack(a, b);
    }
  }

  // BN partials: wave-reduce over lane bits 4-5, then LDS block reduce
  #pragma unroll
  for (int ct = 0; ct < 8; ++ct){
    cs[ct] += __shfl_xor(cs[ct], 16); cs[ct] += __shfl_xor(cs[ct], 32);
    cq[ct] += __shfl_xor(cq[ct], 16); cq[ct] += __shfl_xor(cq[ct], 32);
  }
  __syncthreads();                  // y tile consumed; reuse LDS
  float* red = reinterpret_cast<float*>(lds);
  if (lane < 16){
    #pragma unroll
    for (int ct = 0; ct < 8; ++ct){
      int col = ct*16 + lane;
      red[wave*256 + 2*col]     = cs[ct];
      red[wave*256 + 2*col + 1] = cq[ct];
    }
  }
  __syncthreads();
  if (threadIdx.x < 256){
    float t = 0.f;
    #pragma unroll
    for (int w = 0; w < 8; ++w) t += red[w*256 + threadIdx.x];
    atomicAdd(colsum + threadIdx.x, t);
  }
}

// ---- BN finalize (per-block) + read bf16 y in place, write f32 ----
__global__ __launch_bounds__(256) void k_norm(float* out, const float* __restrict__ colsum,
                       const float* __restrict__ gamma, const float* __restrict__ beta,
                       float fN, int N){
  __shared__ float sc[256];
  if (threadIdx.x < 128){
    int c = threadIdx.x;
    float mean = colsum[2*c] / fN;
    float var  = fmaxf(colsum[2*c + 1] / fN - mean*mean, 0.f);
    float s = gamma[c] * rsqrtf(var + 1e-5f);
    sc[c] = s;
    sc[128 + c] = beta[c] - mean * s;
  }
  __syncthreads();
  const int lane = threadIdx.x & 63;
  const int wv   = threadIdx.x >> 6;
  unsigned* out_u = reinterpret_cast<unsigned*>(out);
  const int rowsPerIter = gridDim.x * 16;              // 4 waves * 4 rows
  for (int r0 = (blockIdx.x*4 + wv)*4; r0 < N; r0 += rowsPerIter){
    int rr = r0 + (lane >> 4);
    int d  = (lane & 15) * 4;          // packed dword offset
    if (rr < N){
      uint4 p = *reinterpret_cast<uint4*>(&out_u[(size_t)rr*128 + d]);
      int c0 = d*2;
      float4 o1, o2;
      o1.x = blo(p.x)*sc[c0+0] + sc[128+c0+0];
      o1.y = bhi(p.x)*sc[c0+1] + sc[128+c0+1];
      o1.z = blo(p.y)*sc[c0+2] + sc[128+c0+2];
      o1.w = bhi(p.y)*sc[c0+3] + sc[128+c0+3];
      o2.x = blo(p.z)*sc[c0+4] + sc[128+c0+4];
      o2.y = bhi(p.z)*sc[c0+5] + sc[128+c0+5];
      o2.z = blo(p.w)*sc[c0+6] + sc[128+c0+6];
      o2.w = bhi(p.w)*sc[c0+7] + sc[128+c0+7];
      *reinterpret_cast<float4*>(&out[(size_t)rr*128 + c0])     = o1;
      *reinterpret_cast<float4*>(&out[(size_t)rr*128 + c0 + 4]) = o2;
    }
  }
}

extern "C" void kernel_launch(void* const* d_in, const int* in_sizes, int n_in,
                              void* d_out, int out_size, void* d_ws, size_t ws_size,
                              hipStream_t stream){
  const float* x     = (const float*)d_in[0];
  const int*   ei    = (const int*)d_in[1];      // int64 staged as int32 by harness
  const float* W     = (const float*)d_in[2];
  const float* b     = (const float*)d_in[3];
  const float* RW    = (const float*)d_in[4];
  const float* rb    = (const float*)d_in[5];
  const float* gamma = (const float*)d_in[6];
  const float* beta  = (const float*)d_in[7];
  float* out = (float*)d_out;
  unsigned* out_u = (unsigned*)d_out;
  const int N = in_sizes[0] / D;
  const int E = in_sizes[1] / 2;

  const int ng   = (N + 8191) >> 13;                       // node groups (8192 each)
  const int gcap = (int)((long long)E * 8192 / N + 4096);  // per-group elist capacity

  char* ws = (char*)d_ws;
  size_t o = 0;
  auto alloc = [&](size_t bytes)->void*{
    void* p = ws + o;
    o += (bytes + 255) & ~size_t(255);
    return p;
  };
  float*    colsum = (float*)alloc(256*4);       // interleaved sum/sumsq; FIRST
  int*      gcur   = (int*)alloc(256);           // group bump cursors; adjacent
  int*      cnt    = (int*)alloc((size_t)N*4);   // adjacent: one memset covers all
  int*      off    = (int*)alloc((size_t)N*4);
  int*      cursor = (int*)alloc((size_t)N*4);
  unsigned* wsW    = (unsigned*)alloc(16384*4);  // swizzled bf16 Wt|RWt
  int*      elist  = (int*)alloc((size_t)ng*gcap*4 + 65536);  // + tail pad

  hipMemsetAsync(ws, 0, 1024 + 256 + (size_t)N*4, stream);  // colsum+gcur+cnt

  int egrid = (E + 255)/256;
  int nb  = (N + 255)/256;        // alloc-scan blocks
  int xbb = (N*32 + 255)/256;     // xb-prep blocks
  k_deg  <<<egrid,         256, 0, stream>>>(ei, cnt, E);
  k_alloc<<<nb + 64 + xbb, 256, 0, stream>>>(cnt, off, cursor, gcur, gcap,
                                             W, RW, wsW, x, out_u, N, nb);
  k_fill <<<512,           256, 0, stream>>>(ei, cursor, elist, E);
  k_agg  <<<4096,          256, 0, stream>>>(out_u, elist, off, cnt, N);
  k_gemm <<<(N + 127)/128, 512, 0, stream>>>(wsW, b, rb, cnt, out, colsum, N);
  k_norm <<<2048,          256, 0, stream>>>(out, colsum, gamma, beta, (float)N, N);
}